// Round 5
// baseline (1539.193 us; speedup 1.0000x reference)
//
#include <hip/hip_runtime.h>
#include <hip/hip_bf16.h>
#include <stdint.h>

typedef __hip_bfloat16 bf16_t;
typedef __attribute__((ext_vector_type(4))) float f32x4;
typedef __attribute__((ext_vector_type(8))) short s16x8;

#define UNITS 768
#define NCOLS 3072        // 4*UNITS (gates, reordered)
#define NPRED 96
#define MROWS 2048
#define BM 64
#define BN 128
#define BK 32
#define NMT 32            // M-tiles (2048/64)

// async global->LDS, 16B per lane, LDS dest = wave-uniform base + lane*16
#define GLL16(ldsp, gp) \
  __builtin_amdgcn_global_load_lds((const __attribute__((address_space(1))) void*)(gp), \
                                   (__attribute__((address_space(3))) void*)(ldsp), 16, 0, 0)

__device__ __forceinline__ float sigf(float x) {
    return __builtin_amdgcn_rcpf(1.f + __expf(-x));
}
__device__ __forceinline__ float tanh_fast(float x) {
    return 1.f - 2.f * __builtin_amdgcn_rcpf(1.f + __expf(2.f * x));
}

// ---------------- prep kernels (once per launch, off critical path) ---------------

__global__ void prep_b0(const float* __restrict__ W_ih, bf16_t* __restrict__ B0T) {
    int idx = blockIdx.x * 256 + threadIdx.x;
    if (idx >= NCOLS * 96) return;
    int c = idx / 96, k = idx % 96;
    int u = ((c >> 6) << 4) + (c & 15);
    int g = (c >> 4) & 3;
    B0T[idx] = (bf16_t)W_ih[(g * UNITS + u) * 96 + k];
}

__global__ void prep_x0(const float* __restrict__ inputs, bf16_t* __restrict__ x0) {
    int idx = blockIdx.x * 256 + threadIdx.x; // < 2048*96 exactly
    int b = idx / 96, k = idx % 96;
    x0[idx] = (bf16_t)inputs[(b * 24 + 23) * 96 + k];
}

__global__ void prep_bias(const float* __restrict__ b_ih, const float* __restrict__ b_hh,
                          const float* __restrict__ W_ih, const float* __restrict__ b_d,
                          float* __restrict__ b0_r, float* __restrict__ beff_r) {
    int c = blockIdx.x * 256 + threadIdx.x;
    if (c >= NCOLS) return;
    int u = ((c >> 6) << 4) + (c & 15);
    int g = (c >> 4) & 3;
    int r = g * UNITS + u;
    float v = b_ih[r] + b_hh[r];
    float acc = 0.f;
    for (int j = 0; j < 96; ++j) acc += W_ih[r * 96 + j] * b_d[j];
    b0_r[c] = v;
    beff_r[c] = v + acc;
}

// BeffT[c][k] = W_hh[r(c)][k] + sum_j W_ih[r(c)][j]*W_d[j][k]   (c<3072, LDS-tiled)
__global__ void prep_beff2(const float* __restrict__ W_hh, const float* __restrict__ W_ih,
                           const float* __restrict__ W_d, bf16_t* __restrict__ BeffT) {
    __shared__ float sWih[64][96];
    __shared__ float sWd[96][64];
    const int c0 = blockIdx.x * 64, k0 = blockIdx.y * 64;
    const int tid = threadIdx.x;
    for (int i = tid; i < 64 * 96; i += 256) {
        int cc = i / 96, j = i % 96;
        int c = c0 + cc;
        int u = ((c >> 6) << 4) + (c & 15);
        int g = (c >> 4) & 3;
        sWih[cc][j] = W_ih[(g * UNITS + u) * 96 + j];
    }
    for (int i = tid; i < 96 * 64; i += 256) {
        int j = i / 64, kk = i % 64;
        sWd[j][kk] = W_d[j * UNITS + k0 + kk];
    }
    __syncthreads();
    const int kk = tid & 63;
    const int cc0 = (tid >> 6) * 16;
    for (int cc = cc0; cc < cc0 + 16; ++cc) {
        float acc = 0.f;
#pragma unroll 12
        for (int j = 0; j < 96; ++j) acc += sWih[cc][j] * sWd[j][kk];
        int c = c0 + cc;
        int u = ((c >> 6) << 4) + (c & 15);
        int g = (c >> 4) & 3;
        int r = g * UNITS + u;
        BeffT[(size_t)c * UNITS + k0 + kk] = (bf16_t)(W_hh[(size_t)r * UNITS + k0 + kk] + acc);
    }
}

// rows 3072..3199 of BeffT: W_d rows then zero pad
__global__ void prep_wdt(const float* __restrict__ W_d, bf16_t* __restrict__ BeffT) {
    int idx = blockIdx.x * 256 + threadIdx.x; // 128*768
    int c = idx / UNITS, k = idx % UNITS;
    float v = (c < NPRED) ? W_d[c * UNITS + k] : 0.f;
    BeffT[(size_t)(NCOLS + c) * UNITS + k] = (bf16_t)v;
}

// ---------------- main step kernel: BM=64 tiles for 2x wave parallelism ---------------
// grid 1-D (divisible by 8). XCD swizzle: blk%8 -> XCD; g = (blk&7)*per + blk>>3;
// consecutive g share nt so each XCD's B-slice (~0.6 MB) lives in its L2.
// Per block: 64x128 tile, 4 waves, wave-tile 32x64 (acc 2x4 of 16x16).
// K-loop: R2's single-barrier ping-pong (sync; ds_read cur; stage next; MFMA).
__global__ __launch_bounds__(256, 4)
void step_kernel(const bf16_t* __restrict__ A,
                 const bf16_t* __restrict__ BT,
                 const float* __restrict__ bias_r,
                 const float* __restrict__ b_d,
                 float* __restrict__ c_state,
                 bf16_t* __restrict__ h_out,
                 float* __restrict__ out,
                 int Kdim, int nt_off, int t, int is_first)
{
    __shared__ bf16_t sA0[BM * BK];   // 4 KB
    __shared__ bf16_t sB0[BN * BK];   // 8 KB
    __shared__ bf16_t sA1[BM * BK];
    __shared__ bf16_t sB1[BN * BK];

    const int tid = threadIdx.x;
    const int wave = tid >> 6;
    const int lane = tid & 63;
    const int wr = wave >> 1, wc = wave & 1;     // wave-tile: rows wr*32, cols wc*64
    const int l15 = lane & 15, l4 = lane >> 4;

    const int per = gridDim.x >> 3;
    const int g = (blockIdx.x & 7) * per + (blockIdx.x >> 3);
    const int nt = nt_off + (g >> 5);
    const int mt = g & 31;
    const int m0 = mt * BM;
    const int n0 = nt * BN;
    const bool is_pred = (nt >= 24);

    const int o0 = wave * 1024 + lane * 16;   // byte offset pattern
    const int nk = Kdim >> 5;

    // stage kt into (dstA, dstB): A one GLL16/thread (4 KB), B two (8 KB)
#define STAGE(dstA, dstB, KT) do {                                                  \
        const int _k0 = (KT) << 5;                                                  \
        {                                                                           \
            int _row = o0 >> 6;                                                     \
            int _kb = o0 & 63;                                                      \
            const bf16_t* _gA = A + (size_t)(m0 + _row) * Kdim + _k0 + (_kb >> 1);  \
            GLL16((dstA) + ((wave * 1024) >> 1), _gA);                              \
        }                                                                           \
        _Pragma("unroll")                                                           \
        for (int _r = 0; _r < 2; ++_r) {                                            \
            int _ob = o0 + _r * 4096;                                               \
            int _row = _ob >> 6;                                                    \
            int _kb = _ob & 63;                                                     \
            const bf16_t* _gB = BT + (size_t)(n0 + _row) * Kdim + _k0 + (_kb >> 1); \
            GLL16((dstB) + ((wave * 1024 + _r * 4096) >> 1), _gB);                  \
        }                                                                           \
    } while (0)

    STAGE(sA0, sB0, 0);

    // ---- pre-loop operand loads (latency hides behind K-loop) ----
    const int u = nt * 32 + wc * 16 + l15;
    const int slot = nt * NMT + mt;
    float* cbase = c_state + (((size_t)slot * 4 + wave) * 64 + lane) * 8;
    f32x4 cold4[2];
    float bi[4];
    cold4[0] = f32x4{0.f, 0.f, 0.f, 0.f};
    cold4[1] = f32x4{0.f, 0.f, 0.f, 0.f};
    if (!is_pred) {
        if (!is_first) {
            cold4[0] = *(const f32x4*)(cbase);
            cold4[1] = *(const f32x4*)(cbase + 4);
        }
#pragma unroll
        for (int f = 0; f < 4; ++f) bi[f] = bias_r[n0 + wc * 64 + f * 16 + l15];
    } else {
#pragma unroll
        for (int f = 0; f < 4; ++f) {
            int j = wc * 64 + f * 16 + l15;
            bi[f] = (j < NPRED) ? b_d[j] : 0.f;
        }
    }

    f32x4 acc[2][4];
#pragma unroll
    for (int i = 0; i < 2; ++i)
#pragma unroll
        for (int j = 0; j < 4; ++j) acc[i][j] = f32x4{0.f, 0.f, 0.f, 0.f};

    for (int kt = 0; kt < nk; ++kt) {
        __syncthreads();   // buf[kt] staging complete (all waves)

        const char* sAc = (kt & 1) ? (const char*)sA1 : (const char*)sA0;
        const char* sBc = (kt & 1) ? (const char*)sB1 : (const char*)sB0;

        s16x8 af[2], bfr[4];
#pragma unroll
        for (int i = 0; i < 2; ++i)
            af[i]  = *(const s16x8*)(sAc + (wr * 32 + i * 16 + l15) * 64 + l4 * 16);
#pragma unroll
        for (int f = 0; f < 4; ++f)
            bfr[f] = *(const s16x8*)(sBc + (wc * 64 + f * 16 + l15) * 64 + l4 * 16);

        // issue next-tile staging into the other buffer; drains at next barrier
        if (kt + 1 < nk) {
            if (kt & 1) { STAGE(sA0, sB0, kt + 1); }
            else        { STAGE(sA1, sB1, kt + 1); }
        }

#pragma unroll
        for (int i = 0; i < 2; ++i)
#pragma unroll
            for (int j = 0; j < 4; ++j)
                acc[i][j] = __builtin_amdgcn_mfma_f32_16x16x32_bf16(af[i], bfr[j], acc[i][j], 0, 0, 0);
    }
#undef STAGE

    // ---- epilogue ----
    if (!is_pred) {
        f32x4 cnew4[2];
#pragma unroll
        for (int i = 0; i < 2; ++i) {
#pragma unroll
            for (int r = 0; r < 4; ++r) {
                int row = m0 + wr * 32 + i * 16 + l4 * 4 + r;
                float gi = acc[i][0][r] + bi[0];
                float gf = acc[i][1][r] + bi[1];
                float gg = acc[i][2][r] + bi[2];
                float go = acc[i][3][r] + bi[3];
                float si = sigf(gi);
                float sf = sigf(gf);
                float tg = tanh_fast(gg);
                float so = sigf(go);
                float cn = sf * cold4[i][r] + si * tg;
                cnew4[i][r] = cn;
                h_out[(size_t)row * UNITS + u] = (bf16_t)(so * tanh_fast(cn));
            }
        }
        *(f32x4*)(cbase)     = cnew4[0];
        *(f32x4*)(cbase + 4) = cnew4[1];
    } else {
#pragma unroll
        for (int f = 0; f < 4; ++f) {
            int j = wc * 64 + f * 16 + l15;
            if (j < NPRED) {
#pragma unroll
                for (int i = 0; i < 2; ++i)
#pragma unroll
                    for (int r = 0; r < 4; ++r) {
                        int row = m0 + wr * 32 + i * 16 + l4 * 4 + r;
                        out[((size_t)row * 64 + (t - 1)) * NPRED + j] = acc[i][f][r] + bi[f];
                    }
            }
        }
    }
}

extern "C" void kernel_launch(void* const* d_in, const int* in_sizes, int n_in,
                              void* d_out, int out_size, void* d_ws, size_t ws_size,
                              hipStream_t stream)
{
    const float* inputs = (const float*)d_in[0];
    const float* W_ih   = (const float*)d_in[1];
    const float* W_hh   = (const float*)d_in[2];
    const float* b_ih   = (const float*)d_in[3];
    const float* b_hh   = (const float*)d_in[4];
    const float* W_d    = (const float*)d_in[5];
    const float* b_d    = (const float*)d_in[6];
    float* out = (float*)d_out;

    char* ws = (char*)d_ws;
    size_t off = 0;
    auto alloc = [&](size_t bytes) -> char* {
        char* p = ws + off;
        off = (off + bytes + 255) & ~(size_t)255;
        return p;
    };
    bf16_t* B0T   = (bf16_t*)alloc((size_t)NCOLS * 96 * 2);
    bf16_t* BeffT = (bf16_t*)alloc((size_t)3200 * UNITS * 2);
    bf16_t* x0    = (bf16_t*)alloc((size_t)MROWS * 96 * 2);
    bf16_t* h0    = (bf16_t*)alloc((size_t)MROWS * UNITS * 2);
    bf16_t* h1    = (bf16_t*)alloc((size_t)MROWS * UNITS * 2);
    float*  cst   = (float*)alloc((size_t)800 * 4 * 64 * 8 * 4);  // tile-major c
    float*  b0r   = (float*)alloc(NCOLS * 4);
    float*  beffr = (float*)alloc(NCOLS * 4);

    prep_b0   <<<(NCOLS * 96 + 255) / 256, 256, 0, stream>>>(W_ih, B0T);
    prep_x0   <<<(MROWS * 96) / 256, 256, 0, stream>>>(inputs, x0);
    prep_bias <<<(NCOLS + 255) / 256, 256, 0, stream>>>(b_ih, b_hh, W_ih, b_d, b0r, beffr);
    prep_beff2<<<dim3(48, 12), 256, 0, stream>>>(W_hh, W_ih, W_d, BeffT);
    prep_wdt  <<<(128 * UNITS) / 256, 256, 0, stream>>>(W_d, BeffT);

    bf16_t* h[2] = {h0, h1};

    // iter 0: gates from x0 (K=96), h=c=0, no pred tiles (24 nt x 32 mt = 768 blocks)
    step_kernel<<<768, 256, 0, stream>>>(x0, B0T, b0r, b_d, cst, h[1], out, 96, 0, 0, 1);
    // iters 1..63: gates_n + pred_{n-1} columns (25 nt x 32 mt = 800 blocks, K=768)
    for (int n = 1; n < 64; ++n)
        step_kernel<<<800, 256, 0, stream>>>(h[n & 1], BeffT, beffr, b_d, cst,
                                             h[(n + 1) & 1], out, UNITS, 0, n, 0);
    // tail: pred_63 = h_64 @ W_d^T + b_d (pred tiles only, 32 blocks)
    step_kernel<<<32, 256, 0, stream>>>(h[0], BeffT, beffr, b_d, cst, h[1], out,
                                        UNITS, 24, 64, 0);
    (void)ws_size; (void)in_sizes; (void)n_in; (void)out_size;
}

// Round 6
// 1348.877 us; speedup vs baseline: 1.1411x; 1.1411x over previous
//
#include <hip/hip_runtime.h>
#include <hip/hip_bf16.h>
#include <stdint.h>

typedef __hip_bfloat16 bf16_t;
typedef __attribute__((ext_vector_type(4))) float f32x4;
typedef __attribute__((ext_vector_type(8))) short s16x8;

#define UNITS 768
#define NCOLS 3072        // 4*UNITS (gates, reordered)
#define NPRED 96
#define MROWS 2048

__device__ __forceinline__ float sigf(float x) {
    return __builtin_amdgcn_rcpf(1.f + __expf(-x));
}
__device__ __forceinline__ float tanh_fast(float x) {
    return 1.f - 2.f * __builtin_amdgcn_rcpf(1.f + __expf(2.f * x));
}

// ---------------- prep kernels (once per launch, off critical path) ---------------

// B0T[c][k] = W_ih[g*768+u][k], c-reordered (linear), K=96
__global__ void prep_b0(const float* __restrict__ W_ih, bf16_t* __restrict__ B0T) {
    int idx = blockIdx.x * 256 + threadIdx.x;
    if (idx >= NCOLS * 96) return;
    int c = idx / 96, k = idx % 96;
    int u = ((c >> 6) << 4) + (c & 15);
    int g = (c >> 4) & 3;
    B0T[idx] = (bf16_t)W_ih[(g * UNITS + u) * 96 + k];
}

// x0 in A-fragment layout: elem((mf*3+kf)*512 + l*8 + j) = x[mf*16+(l&15)][kf*32+(l>>4)*8+j]
__global__ void prep_x0(const float* __restrict__ inputs, bf16_t* __restrict__ x0) {
    int idx = blockIdx.x * 256 + threadIdx.x; // 2048*96 = 196608 exactly
    int j = idx & 7;
    int l = (idx >> 3) & 63;
    int fg = idx >> 9;          // mf*3 + kf
    int kf = fg % 3;
    int mf = fg / 3;
    int m = mf * 16 + (l & 15);
    int k = kf * 32 + (l >> 4) * 8 + j;
    x0[idx] = (bf16_t)inputs[(m * 24 + 23) * 96 + k];
}

__global__ void prep_bias(const float* __restrict__ b_ih, const float* __restrict__ b_hh,
                          const float* __restrict__ W_ih, const float* __restrict__ b_d,
                          float* __restrict__ b0_r, float* __restrict__ beff_r) {
    int c = blockIdx.x * 256 + threadIdx.x;
    if (c >= NCOLS) return;
    int u = ((c >> 6) << 4) + (c & 15);
    int g = (c >> 4) & 3;
    int r = g * UNITS + u;
    float v = b_ih[r] + b_hh[r];
    float acc = 0.f;
    for (int j = 0; j < 96; ++j) acc += W_ih[r * 96 + j] * b_d[j];
    b0_r[c] = v;
    beff_r[c] = v + acc;
}

// BeffT[c][k] = W_hh[r(c)][k] + sum_j W_ih[r(c)][j]*W_d[j][k]   (c<3072, LDS-tiled)
__global__ void prep_beff2(const float* __restrict__ W_hh, const float* __restrict__ W_ih,
                           const float* __restrict__ W_d, bf16_t* __restrict__ BeffT) {
    __shared__ float sWih[64][96];
    __shared__ float sWd[96][64];
    const int c0 = blockIdx.x * 64, k0 = blockIdx.y * 64;
    const int tid = threadIdx.x;
    for (int i = tid; i < 64 * 96; i += 256) {
        int cc = i / 96, j = i % 96;
        int c = c0 + cc;
        int u = ((c >> 6) << 4) + (c & 15);
        int g = (c >> 4) & 3;
        sWih[cc][j] = W_ih[(g * UNITS + u) * 96 + j];
    }
    for (int i = tid; i < 96 * 64; i += 256) {
        int j = i / 64, kk = i % 64;
        sWd[j][kk] = W_d[j * UNITS + k0 + kk];
    }
    __syncthreads();
    const int kk = tid & 63;
    const int cc0 = (tid >> 6) * 16;
    for (int cc = cc0; cc < cc0 + 16; ++cc) {
        float acc = 0.f;
#pragma unroll 12
        for (int j = 0; j < 96; ++j) acc += sWih[cc][j] * sWd[j][kk];
        int c = c0 + cc;
        int u = ((c >> 6) << 4) + (c & 15);
        int g = (c >> 4) & 3;
        int r = g * UNITS + u;
        BeffT[(size_t)c * UNITS + k0 + kk] = (bf16_t)(W_hh[(size_t)r * UNITS + k0 + kk] + acc);
    }
}

// rows 3072..3199 of BeffT: W_d rows then zero pad
__global__ void prep_wdt(const float* __restrict__ W_d, bf16_t* __restrict__ BeffT) {
    int idx = blockIdx.x * 256 + threadIdx.x; // 128*768
    int c = idx / UNITS, k = idx % UNITS;
    float v = (c < NPRED) ? W_d[c * UNITS + k] : 0.f;
    BeffT[(size_t)(NCOLS + c) * UNITS + k] = (bf16_t)v;
}

// swizzle linear [c][K] (c pre-reordered) -> B-fragment order:
// elem((((nw*Knk + kf)*4 + f)*64 + l)*8 + j) = src[c][k],
//   c = (nw>>1)*128 + (nw&1)*64 + f*16 + (l&15),  k = kf*32 + (l>>4)*8 + j
__global__ void prep_swz(const bf16_t* __restrict__ src, bf16_t* __restrict__ dst,
                         int Knk, int K, int total) {
    int idx = blockIdx.x * 256 + threadIdx.x;
    if (idx >= total) return;
    int j = idx & 7;
    int l = (idx >> 3) & 63;
    int fg = idx >> 9;
    int f = fg & 3;
    int rest = fg >> 2;
    int kf = rest % Knk;
    int nw = rest / Knk;
    int c = (nw >> 1) * 128 + (nw & 1) * 64 + f * 16 + (l & 15);
    int k = kf * 32 + (l >> 4) * 8 + j;
    dst[idx] = src[(size_t)c * K + k];
}

// ---------------- main step kernel: no LDS, no barriers ---------------
// A and B both pre-swizzled to MFMA fragment order -> K-loop is pure
// global_load_dwordx4 (to VGPR) + MFMA with compiler-managed vmcnt(N).
// grid 1-D; XCD swizzle blk%8 -> XCD; g=(blk&7)*per+blk>>3; nt=g>>4, mt=g&15.
// Block 128x128; wave (wr,wc) computes 64x64; 3-slot register pipeline, 2-deep prefetch.
// h written by epilogue directly in A-fragment layout for the next step.
__global__ __launch_bounds__(256, 2)
void step_kernel(const bf16_t* __restrict__ A,
                 const bf16_t* __restrict__ B,
                 const float* __restrict__ bias_r,
                 const float* __restrict__ b_d,
                 float* __restrict__ c_state,
                 bf16_t* __restrict__ h_out,
                 float* __restrict__ out,
                 int Knk, int nt_off, int t, int is_first)
{
    const int tid = threadIdx.x;
    const int wave = tid >> 6;
    const int lane = tid & 63;
    const int wr = wave >> 1, wc = wave & 1;
    const int l15 = lane & 15, l4 = lane >> 4;

    const int per = gridDim.x >> 3;
    const int g = (blockIdx.x & 7) * per + (blockIdx.x >> 3);
    const int nt = nt_off + (g >> 4);
    const int mt = g & 15;
    const int n0 = nt * 128;
    const bool is_pred = (nt >= 24);

    // fragment base pointers (elements); per-kt strides: A 512, B 2048
    const bf16_t* Ab[4];
#pragma unroll
    for (int i = 0; i < 4; ++i)
        Ab[i] = A + ((size_t)((mt * 8 + wr * 4 + i) * Knk) * 64 + lane) * 8;
    const bf16_t* Bb[4];
#pragma unroll
    for (int f = 0; f < 4; ++f)
        Bb[f] = B + ((size_t)((nt * 2 + wc) * Knk * 4 + f) * 64 + lane) * 8;

    // ---- hoisted epilogue operands ----
    const int u = nt * 32 + wc * 16 + l15;
    const int slot = nt * 16 + mt;
    float* cbase = c_state + (((size_t)slot * 4 + wave) * 64 + lane) * 16;
    f32x4 cold4[4];
    float bi[4];
#pragma unroll
    for (int q = 0; q < 4; ++q) cold4[q] = f32x4{0.f, 0.f, 0.f, 0.f};
    if (!is_pred) {
        if (!is_first) {
#pragma unroll
            for (int q = 0; q < 4; ++q) cold4[q] = *(const f32x4*)(cbase + q * 4);
        }
#pragma unroll
        for (int f = 0; f < 4; ++f) bi[f] = bias_r[n0 + wc * 64 + f * 16 + l15];
    } else {
#pragma unroll
        for (int f = 0; f < 4; ++f) {
            int j = wc * 64 + f * 16 + l15;
            bi[f] = (j < NPRED) ? b_d[j] : 0.f;
        }
    }

    f32x4 acc[4][4];
#pragma unroll
    for (int i = 0; i < 4; ++i)
#pragma unroll
        for (int j = 0; j < 4; ++j) acc[i][j] = f32x4{0.f, 0.f, 0.f, 0.f};

    s16x8 afr[3][4], bfr[3][4];
    const int nk = Knk;

#define LOADK(BUF, KT) do {                                                          \
        _Pragma("unroll")                                                            \
        for (int _i = 0; _i < 4; ++_i)                                               \
            afr[BUF][_i] = *(const s16x8*)(Ab[_i] + (size_t)(KT) * 512);             \
        _Pragma("unroll")                                                            \
        for (int _f = 0; _f < 4; ++_f)                                               \
            bfr[BUF][_f] = *(const s16x8*)(Bb[_f] + (size_t)(KT) * 2048);            \
    } while (0)
#define MF(BUF) do {                                                                 \
        _Pragma("unroll")                                                            \
        for (int _i = 0; _i < 4; ++_i)                                               \
            _Pragma("unroll")                                                        \
            for (int _j = 0; _j < 4; ++_j)                                           \
                acc[_i][_j] = __builtin_amdgcn_mfma_f32_16x16x32_bf16(               \
                    afr[BUF][_i], bfr[BUF][_j], acc[_i][_j], 0, 0, 0);               \
    } while (0)

    LOADK(0, 0);
    LOADK(1, 1);
    const int nk3 = nk / 3;   // nk is 3 or 24
    for (int b3 = 0; b3 < nk3; ++b3) {
        const int kt = b3 * 3;
        if (kt + 2 < nk) LOADK(2, kt + 2);
        MF(0);
        if (kt + 3 < nk) LOADK(0, kt + 3);
        MF(1);
        if (kt + 4 < nk) LOADK(1, kt + 4);
        MF(2);
    }
#undef LOADK
#undef MF

    // ---- epilogue ----
    if (!is_pred) {
        // write h in A-fragment layout: kf = nt; lane' = (row&15) | (kquad<<4); elem j = u&7
        const int kq = wc * 2 + (l15 >> 3);
        const int jj = l15 & 7;
        f32x4 cnew4[4];
#pragma unroll
        for (int i = 0; i < 4; ++i) {
            const int mf = mt * 8 + wr * 4 + i;
            bf16_t* hb = h_out + (size_t)(mf * 24 + nt) * 512;
#pragma unroll
            for (int r = 0; r < 4; ++r) {
                float gi = acc[i][0][r] + bi[0];
                float gf = acc[i][1][r] + bi[1];
                float gg = acc[i][2][r] + bi[2];
                float go = acc[i][3][r] + bi[3];
                float si = sigf(gi);
                float sf = sigf(gf);
                float tg = tanh_fast(gg);
                float so = sigf(go);
                float cn = sf * cold4[i][r] + si * tg;
                cnew4[i][r] = cn;
                int lp = (l4 * 4 + r) | (kq << 4);
                hb[lp * 8 + jj] = (bf16_t)(so * tanh_fast(cn));
            }
        }
#pragma unroll
        for (int q = 0; q < 4; ++q) *(f32x4*)(cbase + q * 4) = cnew4[q];
    } else {
#pragma unroll
        for (int f = 0; f < 4; ++f) {
            int j = wc * 64 + f * 16 + l15;
            if (j < NPRED) {
#pragma unroll
                for (int i = 0; i < 4; ++i)
#pragma unroll
                    for (int r = 0; r < 4; ++r) {
                        int row = mt * 128 + wr * 64 + i * 16 + l4 * 4 + r;
                        out[((size_t)row * 64 + (t - 1)) * NPRED + j] = acc[i][f][r] + bi[f];
                    }
            }
        }
    }
}

extern "C" void kernel_launch(void* const* d_in, const int* in_sizes, int n_in,
                              void* d_out, int out_size, void* d_ws, size_t ws_size,
                              hipStream_t stream)
{
    const float* inputs = (const float*)d_in[0];
    const float* W_ih   = (const float*)d_in[1];
    const float* W_hh   = (const float*)d_in[2];
    const float* b_ih   = (const float*)d_in[3];
    const float* b_hh   = (const float*)d_in[4];
    const float* W_d    = (const float*)d_in[5];
    const float* b_d    = (const float*)d_in[6];
    float* out = (float*)d_out;

    char* ws = (char*)d_ws;
    size_t off = 0;
    auto alloc = [&](size_t bytes) -> char* {
        char* p = ws + off;
        off = (off + bytes + 255) & ~(size_t)255;
        return p;
    };
    bf16_t* B0T   = (bf16_t*)alloc((size_t)NCOLS * 96 * 2);       // linear temp
    bf16_t* B0s   = (bf16_t*)alloc((size_t)NCOLS * 96 * 2);       // frag-swizzled
    bf16_t* BeffT = (bf16_t*)alloc((size_t)3200 * UNITS * 2);     // linear temp
    bf16_t* Bs    = (bf16_t*)alloc((size_t)3200 * UNITS * 2);     // frag-swizzled
    bf16_t* x0s   = (bf16_t*)alloc((size_t)MROWS * 96 * 2);       // frag layout
    bf16_t* h0    = (bf16_t*)alloc((size_t)MROWS * UNITS * 2);    // frag layout
    bf16_t* h1    = (bf16_t*)alloc((size_t)MROWS * UNITS * 2);
    float*  cst   = (float*)alloc((size_t)384 * 4 * 64 * 16 * 4); // tile-major c
    float*  b0r   = (float*)alloc(NCOLS * 4);
    float*  beffr = (float*)alloc(NCOLS * 4);

    prep_b0   <<<(NCOLS * 96 + 255) / 256, 256, 0, stream>>>(W_ih, B0T);
    prep_swz  <<<(NCOLS * 96 + 255) / 256, 256, 0, stream>>>(B0T, B0s, 3, 96, NCOLS * 96);
    prep_x0   <<<(MROWS * 96) / 256, 256, 0, stream>>>(inputs, x0s);
    prep_bias <<<(NCOLS + 255) / 256, 256, 0, stream>>>(b_ih, b_hh, W_ih, b_d, b0r, beffr);
    prep_beff2<<<dim3(48, 12), 256, 0, stream>>>(W_hh, W_ih, W_d, BeffT);
    prep_wdt  <<<(128 * UNITS) / 256, 256, 0, stream>>>(W_d, BeffT);
    prep_swz  <<<(3200 * UNITS + 255) / 256, 256, 0, stream>>>(BeffT, Bs, 24, UNITS, 3200 * UNITS);

    bf16_t* h[2] = {h0, h1};

    // iter 0: gates from x0 (Knk=3), h=c=0, no pred tiles (24 nt x 16 mt = 384 blocks)
    step_kernel<<<384, 256, 0, stream>>>(x0s, B0s, b0r, b_d, cst, h[1], out, 3, 0, 0, 1);
    // iters 1..63: gates_n + pred_{n-1} columns (25 nt x 16 mt = 400 blocks, Knk=24)
    for (int n = 1; n < 64; ++n)
        step_kernel<<<400, 256, 0, stream>>>(h[n & 1], Bs, beffr, b_d, cst,
                                             h[(n + 1) & 1], out, 24, 0, n, 0);
    // tail: pred_63 (pred tiles only, 16 blocks)
    step_kernel<<<16, 256, 0, stream>>>(h[0], Bs, beffr, b_d, cst, h[1], out,
                                        24, 24, 64, 0);
    (void)ws_size; (void)in_sizes; (void)n_in; (void)out_size;
}